// Round 3
// baseline (601.823 us; speedup 1.0000x reference)
//
#include <hip/hip_runtime.h>
#include <stdint.h>

#define Bz 4
#define Sz 4096
#define Dz 2048
#define Hz 16
#define HDz 128
#define NTz 8
#define TILEz 16

typedef __bf16 bf16x8 __attribute__((ext_vector_type(8)));
typedef float f32x4 __attribute__((ext_vector_type(4)));
typedef float fx4 __attribute__((ext_vector_type(4)));
typedef unsigned short u16;
typedef u16 u16x4 __attribute__((ext_vector_type(4)));
typedef u16 u16x8 __attribute__((ext_vector_type(8)));

#define MFMA16(a, b, c) __builtin_amdgcn_mfma_f32_16x16x32_bf16((a), (b), (c), 0, 0, 0)

__device__ __forceinline__ u16 f2bf(float f) {
    uint32_t u = __builtin_bit_cast(uint32_t, f);
    return (u16)((u + 0x7fffu + ((u >> 16) & 1u)) >> 16);  // RNE
}

// async global->LDS, 16B per lane. LDS dest must be wave-uniform base; HW adds lane*16.
__device__ __forceinline__ void async16(const u16* g, u16* l) {
    __builtin_amdgcn_global_load_lds(
        (const __attribute__((address_space(1))) unsigned int*)(g),
        (__attribute__((address_space(3))) unsigned int*)(l), 16, 0, 0);
}

#define BAR()                                  \
    do {                                       \
        asm volatile("" ::: "memory");         \
        __builtin_amdgcn_s_barrier();          \
        asm volatile("" ::: "memory");         \
    } while (0)

// ---------------- convert x (fp32 -> bf16), 8 elems/thread ----------------
__global__ void cvt_x(const float* __restrict__ x, u16* __restrict__ o) {
    int i = blockIdx.x * 256 + threadIdx.x;
    const fx4* xv = (const fx4*)x;
    fx4 a = xv[i * 2], b = xv[i * 2 + 1];
    u16x8 r;
    r[0] = f2bf(a[0]); r[1] = f2bf(a[1]); r[2] = f2bf(a[2]); r[3] = f2bf(a[3]);
    r[4] = f2bf(b[0]); r[5] = f2bf(b[1]); r[6] = f2bf(b[2]); r[7] = f2bf(b[3]);
    ((u16x8*)o)[i] = r;
}

// ---------------- transpose + convert weights: (2048 x 2048) fp32 -> bf16 N x K ----------------
// vectorized: fx4 loads, u16x4 LDS writes, u16x4 global stores (was 2B scalar stores)
__global__ void transpose_cvt(const float* W0, const float* W1, const float* W2, const float* W3,
                              u16* O0, u16* O1, u16* O2, u16* O3) {
    const float* W; u16* O;
    switch (blockIdx.z) {
        case 0: W = W0; O = O0; break;
        case 1: W = W1; O = O1; break;
        case 2: W = W2; O = O2; break;
        default: W = W3; O = O3; break;
    }
    __shared__ __align__(16) u16 tile[32][36];  // pad 32->36 (72B rows, 8B-aligned segs)
    int bx = blockIdx.x * 32, by = blockIdx.y * 32;
    int tid = threadIdx.y * 32 + threadIdx.x;
    int row = tid >> 3, c4 = tid & 7;
    fx4 wv = *(const fx4*)&W[(long)(by + row) * 2048 + bx + c4 * 4];
    u16x4 t4;
    t4[0] = f2bf(wv[0]); t4[1] = f2bf(wv[1]); t4[2] = f2bf(wv[2]); t4[3] = f2bf(wv[3]);
    *(u16x4*)&tile[row][c4 * 4] = t4;
    __syncthreads();
    u16x4 o4;
#pragma unroll
    for (int c = 0; c < 4; ++c) o4[c] = tile[c4 * 4 + c][row];
    *(u16x4*)&O[(long)(bx + row) * 2048 + by + c4 * 4] = o4;
}

// ---------------- 256x256 pipelined GEMM: C(MxN) = A(MxK) * BT(NxK)^T, bf16 in ----------------
// v3: register-fragment software pipeline. Phase p issues ds_reads for phase p+1, then MFMAs
// phase p's (already-loaded) frags -> LDS-read latency overlaps MFMA. One barrier per phase
// (4/tile, was 8). lgkmcnt(0)+sched_barrier(0) at phase end orders frag loads vs next MFMA
// (rule #18). vmcnt(6) twice per tile: P0-end (tile g kh1 landed), P2-end (tile g+1 kh0 landed);
// never drains to 0. Staging writes only target regions whose readers completed before a barrier.
__device__ __forceinline__ void stage2(const u16* s0, const u16* s1, u16* chunk, int w, int koff) {
    async16(s0 + koff, chunk + w * 512);
    async16(s1 + koff, chunk + w * 512 + 4096);
}

template <typename OutT>
__global__ __launch_bounds__(512, 2) void gemm256(const u16* __restrict__ A, const u16* __restrict__ BT,
                                                  OutT* __restrict__ C, int M_, int N_, int K_) {
    __shared__ __align__(1024) u16 lds[65536];  // 128 KB: A at [0,32768), B at [32768,65536)
    const int t = threadIdx.x, w = t >> 6, l = t & 63, lr = l & 15, quad = l >> 4;
    const int wm = w >> 2, wn = w & 3;
    const int nbn = N_ >> 8;
    const int cpx = gridDim.x >> 3;
    const int swz = (blockIdx.x & 7) * cpx + (blockIdx.x >> 3);
    const int bm = swz / nbn, bn = swz % nbn;

    const u16* sA[2]; const u16* sB[2];
#pragma unroll
    for (int r = 0; r < 2; r++) {
        int idx = r * 512 + t;
        int row = idx >> 2;
        int q = (t & 3) ^ ((row >> 2) & 2);
        sA[r] = A + (long)(bm * 256 + row) * K_ + q * 8;
        sB[r] = BT + (long)(bn * 256 + row) * K_ + q * 8;
    }
    const int qro = (quad ^ (((lr >> 3) & 1) << 1)) * 8;
    const int rowA0 = wm * 128 + lr;
    const int rowB0 = wn * 64 + lr;
    const int nt = K_ >> 6;

    f32x4 acc[8][4] = {};
    bf16x8 bfr_a[4], bfr_b[4], af_a[4], af_b[4];

    // ---- prologue: tile0 (4 chunks) + tile1 kh0 (2 chunks); drain tile0-kh0 (vmcnt 12->8) ----
    stage2(sA[0], sA[1], lds + 0, w, 0);                     // u1: A0 kh0
    stage2(sB[0], sB[1], lds + 32768, w, 0);                 // u2: B0 kh0
    stage2(sA[0], sA[1], lds + 8192, w, 32);                 // u3: A0 kh1
    stage2(sB[0], sB[1], lds + 32768 + 8192, w, 32);         // u4: B0 kh1
    const int k1 = (nt > 1) ? 64 : 0;
    stage2(sA[0], sA[1], lds + 16384, w, k1);                // u5: A1 kh0
    stage2(sB[0], sB[1], lds + 32768 + 16384, w, k1);        // u6: B1 kh0
    asm volatile("s_waitcnt vmcnt(8)" ::: "memory");
    BAR();
    // preload F0 (tile0 kh0)
#pragma unroll
    for (int j = 0; j < 4; ++j) bfr_a[j] = *(const bf16x8*)(lds + 32768 + (rowB0 + j * 16) * 32 + qro);
#pragma unroll
    for (int i = 0; i < 4; ++i) af_a[i] = *(const bf16x8*)(lds + (rowA0 + i * 16) * 32 + qro);
    asm volatile("s_waitcnt lgkmcnt(0)" ::: "memory");
    __builtin_amdgcn_sched_barrier(0);

    for (int g = 0; g < nt; ++g) {
        const int cb = g & 1, ob = cb ^ 1;
        const int t1k = ((g + 1 < nt ? g + 1 : nt - 1) << 6) + 32;
        const int t2k = ((g + 2 < nt ? g + 2 : nt - 1) << 6);
        const u16* Acb = lds + cb * 16384;
        const u16* Bcb = lds + 32768 + cb * 16384;
        const u16* Anx = lds + ob * 16384;
        const u16* Bnx = lds + 32768 + ob * 16384;

        // P0: MFMA F0 (kh0,mh0); load F1 = af_b (A kh0 mh1); stage A-kh1(g+1) -> ob
#pragma unroll
        for (int i = 0; i < 4; ++i) af_b[i] = *(const bf16x8*)(Acb + (rowA0 + 64 + i * 16) * 32 + qro);
        stage2(sA[0], sA[1], (u16*)(lds + ob * 16384 + 8192), w, t1k);
        __builtin_amdgcn_s_setprio(1);
#pragma unroll
        for (int i = 0; i < 4; ++i)
#pragma unroll
            for (int j = 0; j < 4; ++j) acc[i][j] = MFMA16(af_a[i], bfr_a[j], acc[i][j]);
        __builtin_amdgcn_s_setprio(0);
        asm volatile("s_waitcnt lgkmcnt(0)" ::: "memory");
        __builtin_amdgcn_sched_barrier(0);
        asm volatile("s_waitcnt vmcnt(6)" ::: "memory");  // tile g kh1 (u(g-1,P0/P1)) landed
        BAR();

        // P1: MFMA F1 (kh0,mh1); load F2 = bfr_b (B kh1) + af_a (A kh1 mh0); stage B-kh1(g+1) -> ob
#pragma unroll
        for (int j = 0; j < 4; ++j) bfr_b[j] = *(const bf16x8*)(Bcb + 8192 + (rowB0 + j * 16) * 32 + qro);
#pragma unroll
        for (int i = 0; i < 4; ++i) af_a[i] = *(const bf16x8*)(Acb + 8192 + (rowA0 + i * 16) * 32 + qro);
        stage2(sB[0], sB[1], (u16*)(lds + 32768 + ob * 16384 + 8192), w, t1k);
        __builtin_amdgcn_s_setprio(1);
#pragma unroll
        for (int i = 0; i < 4; ++i)
#pragma unroll
            for (int j = 0; j < 4; ++j) acc[4 + i][j] = MFMA16(af_b[i], bfr_a[j], acc[4 + i][j]);
        __builtin_amdgcn_s_setprio(0);
        asm volatile("s_waitcnt lgkmcnt(0)" ::: "memory");
        __builtin_amdgcn_sched_barrier(0);
        BAR();

        // P2: MFMA F2 (kh1,mh0); load F3 = af_b (A kh1 mh1); stage A-kh0(g+2) -> cb
#pragma unroll
        for (int i = 0; i < 4; ++i) af_b[i] = *(const bf16x8*)(Acb + 8192 + (rowA0 + 64 + i * 16) * 32 + qro);
        stage2(sA[0], sA[1], (u16*)(lds + cb * 16384), w, t2k);
        __builtin_amdgcn_s_setprio(1);
#pragma unroll
        for (int i = 0; i < 4; ++i)
#pragma unroll
            for (int j = 0; j < 4; ++j) acc[i][j] = MFMA16(af_a[i], bfr_b[j], acc[i][j]);
        __builtin_amdgcn_s_setprio(0);
        asm volatile("s_waitcnt lgkmcnt(0)" ::: "memory");
        __builtin_amdgcn_sched_barrier(0);
        asm volatile("s_waitcnt vmcnt(6)" ::: "memory");  // tile g+1 kh0 (u(g-1,P2/P3)) landed
        BAR();

        // P3: MFMA F3 (kh1,mh1); load F0' (tile g+1 kh0 from nx buf); stage B-kh0(g+2) -> cb
#pragma unroll
        for (int j = 0; j < 4; ++j) bfr_a[j] = *(const bf16x8*)(Bnx + (rowB0 + j * 16) * 32 + qro);
#pragma unroll
        for (int i = 0; i < 4; ++i) af_a[i] = *(const bf16x8*)(Anx + (rowA0 + i * 16) * 32 + qro);
        stage2(sB[0], sB[1], (u16*)(lds + 32768 + cb * 16384), w, t2k);
        __builtin_amdgcn_s_setprio(1);
#pragma unroll
        for (int i = 0; i < 4; ++i)
#pragma unroll
            for (int j = 0; j < 4; ++j) acc[4 + i][j] = MFMA16(af_b[i], bfr_b[j], acc[4 + i][j]);
        __builtin_amdgcn_s_setprio(0);
        asm volatile("s_waitcnt lgkmcnt(0)" ::: "memory");
        __builtin_amdgcn_sched_barrier(0);
        BAR();
    }

    // ---- epilogue (unchanged mapping: acc[mh*4+i]) ----
    const long crow0 = (long)bm * 256 + wm * 128;
    const int ccol0 = bn * 256 + wn * 64;
#pragma unroll
    for (int f = 0; f < 8; ++f) {
        long row0 = crow0 + (f >> 2) * 64 + (f & 3) * 16 + quad * 4;
#pragma unroll
        for (int j = 0; j < 4; ++j) {
            int col = ccol0 + j * 16 + lr;
#pragma unroll
            for (int rg = 0; rg < 4; ++rg) {
                long idx = (row0 + rg) * N_ + col;
                if constexpr (sizeof(OutT) == 2) ((u16*)C)[idx] = f2bf(acc[f][j][rg]);
                else ((float*)C)[idx] = acc[f][j][rg];
            }
        }
    }
}

// ---------------- sparse K/V projection, split-K=4 over D, fp32 partials ----------------
#define KV_SPLIT 4
#define KV_CHUNK (Dz / KV_SPLIT)
__global__ __launch_bounds__(256) void kv_sparse(const u16* __restrict__ xbf, const u16* __restrict__ WkT,
                                                 const u16* __restrict__ WvT, const int* __restrict__ anchor,
                                                 float* __restrict__ part) {
    const int bh = blockIdx.x, which = blockIdx.y, split = blockIdx.z;
    const int b = bh >> 4, h = bh & 15;
    __shared__ int toks[128];
    __shared__ __align__(16) u16 As[4096];
    __shared__ __align__(16) u16 Bs[4096];
    const int t = threadIdx.x, w = t >> 6, l = t & 63, lr = l & 15, quad = l >> 4;
    if (t < 128) {
        int j = t >> 4;
        int tile = (j == 7) ? (Sz / TILEz - 1) : anchor[bh * NTz + j];
        toks[t] = tile * TILEz + (t & 15);
    }
    __syncthreads();
    const u16* gA[2]; const u16* gB[2]; u16* lA[2]; u16* lB[2];
#pragma unroll
    for (int r = 0; r < 2; r++) {
        int c = r * 256 + t;
        int row = c >> 2, col8 = (c & 3) * 8;
        const u16* xrow = xbf + ((long)b * Sz + toks[row]) * Dz + col8;
        const u16* wrowK = WkT + (long)(h * HDz + row) * Dz + col8;
        const u16* wrowV = WvT + (long)(h * HDz + row) * Dz + col8;
        gA[r] = (which == 0) ? xrow : wrowV;
        gB[r] = (which == 0) ? wrowK : xrow;
        lA[r] = &As[(r * 256 + w * 64) * 8];
        lB[r] = &Bs[(r * 256 + w * 64) * 8];
    }
    f32x4 acc[4][4] = {};
    const int wr = (w >> 1) * 64, wc = (w & 1) * 64;
    const int ks0 = split * KV_CHUNK;
    for (int k0 = ks0; k0 < ks0 + KV_CHUNK; k0 += 32) {
        async16(gA[0] + k0, lA[0]); async16(gA[1] + k0, lA[1]);
        async16(gB[0] + k0, lB[0]); async16(gB[1] + k0, lB[1]);
        __syncthreads();
        bf16x8 af[4], bfr[4];
#pragma unroll
        for (int i = 0; i < 4; i++) af[i] = *(const bf16x8*)&As[(wr + i * 16 + lr) * 32 + quad * 8];
#pragma unroll
        for (int j = 0; j < 4; j++) bfr[j] = *(const bf16x8*)&Bs[(wc + j * 16 + lr) * 32 + quad * 8];
#pragma unroll
        for (int i = 0; i < 4; i++)
#pragma unroll
            for (int j = 0; j < 4; j++) acc[i][j] = MFMA16(af[i], bfr[j], acc[i][j]);
        __syncthreads();
    }
    float* out = part + (((long)split * 2 + which) * 64 + bh) * 16384;
#pragma unroll
    for (int i = 0; i < 4; i++) {
        int row0 = wr + i * 16 + quad * 4;
#pragma unroll
        for (int j = 0; j < 4; j++) {
            int col = wc + j * 16 + lr;
#pragma unroll
            for (int rg = 0; rg < 4; rg++) out[(row0 + rg) * 128 + col] = acc[i][j][rg];
        }
    }
}

// reduce KV_SPLIT fp32 partials -> bf16 kv buffer (ksp || vspT contiguous)
__global__ void kv_reduce(const float* __restrict__ part, u16* __restrict__ kv) {
    long i = ((long)blockIdx.x * 256 + threadIdx.x) * 4;
    const long stride = 2L * 64 * 16384;
    fx4 s = *(const fx4*)(part + i);
#pragma unroll
    for (int sp = 1; sp < KV_SPLIT; sp++) {
        fx4 p = *(const fx4*)(part + sp * stride + i);
        s[0] += p[0]; s[1] += p[1]; s[2] += p[2]; s[3] += p[3];
    }
    u16x4 r;
    r[0] = f2bf(s[0]); r[1] = f2bf(s[1]); r[2] = f2bf(s[2]); r[3] = f2bf(s[3]);
    *(u16x4*)(kv + i) = r;
}

// ---------------- attention: 8 waves/block, K staged in LDS (swizzled) ----------------
__global__ __launch_bounds__(512) void attn_kernel(u16* QAO,
                                                   const u16* __restrict__ ksp, const u16* __restrict__ vspT,
                                                   const int* __restrict__ anchor) {
    const int st = blockIdx.x, h = blockIdx.y, b = blockIdx.z;
    const int bh = b * Hz + h, s0 = st * 128;
    __shared__ __align__(16) u16 Kl[16384];      // 128x128, 16B-chunk XOR-swizzled
    __shared__ __align__(16) u16 Ps[128 * 136];  // pad 128->136
    __shared__ int toks[128];
    const int t = threadIdx.x, w = t >> 6, l = t & 63, lr = l & 15, quad = l >> 4;
    if (t < 128) {
        int j = t >> 4;
        int tile = (j == 7) ? (Sz / TILEz - 1) : anchor[bh * NTz + j];
        toks[t] = tile * TILEz + (t & 15);
    }
    const u16* Qb = QAO + (long)(b * Sz + s0 + w * 16) * 2048 + h * HDz;
    const u16* Kb = ksp + (long)bh * HDz * 128;   // [key][d]
    const u16* Vb = vspT + (long)bh * HDz * 128;  // [d][key]
    bf16x8 qf[4];
#pragma unroll
    for (int ks = 0; ks < 4; ks++)
        qf[ks] = *(const bf16x8*)(Qb + (long)lr * 2048 + ks * 32 + quad * 8);
#pragma unroll
    for (int r = 0; r < 4; r++) {
        int idx = r * 512 + t;
        int row = idx >> 4, c = idx & 15;
        async16(Kb + row * 128 + ((c ^ (row & 7)) * 8), Kl + (r * 512 + w * 64) * 8);
    }
    __syncthreads();
    f32x4 acc[8] = {};
#pragma unroll
    for (int ks = 0; ks < 4; ks++) {
#pragma unroll
        for (int j = 0; j < 8; j++) {
            int kr = j * 16 + lr;
            bf16x8 bj = *(const bf16x8*)(Kl + kr * 128 + (((ks * 4 + quad) ^ (lr & 7)) * 8));
            acc[j] = MFMA16(qf[ks], bj, acc[j]);
        }
    }
    int tokj[8];
#pragma unroll
    for (int j = 0; j < 8; j++) tokj[j] = toks[j * 16 + lr];
    const float scale = 0.08838834764831845f;  // 1/sqrt(128)
#pragma unroll
    for (int rg = 0; rg < 4; rg++) {
        int qpos = s0 + w * 16 + quad * 4 + rg;
        float v[8];
#pragma unroll
        for (int j = 0; j < 8; j++)
            v[j] = (tokj[j] > qpos) ? -1e10f : acc[j][rg] * scale;
        float mx = v[0];
#pragma unroll
        for (int j = 1; j < 8; j++) mx = fmaxf(mx, v[j]);
        mx = fmaxf(mx, __shfl_xor(mx, 1, 64));
        mx = fmaxf(mx, __shfl_xor(mx, 2, 64));
        mx = fmaxf(mx, __shfl_xor(mx, 4, 64));
        mx = fmaxf(mx, __shfl_xor(mx, 8, 64));
        float s = 0.f;
#pragma unroll
        for (int j = 0; j < 8; j++) { v[j] = exp2f((v[j] - mx) * 1.4426950408889634f); s += v[j]; }
        s += __shfl_xor(s, 1, 64);
        s += __shfl_xor(s, 2, 64);
        s += __shfl_xor(s, 4, 64);
        s += __shfl_xor(s, 8, 64);
        float rs = 1.0f / s;
        int prow = w * 16 + quad * 4 + rg;
#pragma unroll
        for (int j = 0; j < 8; j++) Ps[prow * 136 + j * 16 + lr] = f2bf(v[j] * rs);
    }
    bf16x8 va[4];
#pragma unroll
    for (int ks = 0; ks < 4; ks++)
        va[ks] = *(const bf16x8*)(Vb + (w * 16 + lr) * 128 + ks * 32 + quad * 8);
    __syncthreads();
    f32x4 oacc[8] = {};
#pragma unroll
    for (int ks = 0; ks < 4; ks++) {
#pragma unroll
        for (int j = 0; j < 8; j++) {
            bf16x8 pj = *(const bf16x8*)&Ps[(j * 16 + lr) * 136 + ks * 32 + quad * 8];
            oacc[j] = MFMA16(va[ks], pj, oacc[j]);
        }
    }
#pragma unroll
    for (int j = 0; j < 8; j++) {
        u16x4 pk;
#pragma unroll
        for (int rg = 0; rg < 4; rg++) pk[rg] = f2bf(oacc[j][rg]);
        int d = w * 16 + quad * 4;
        int q = j * 16 + lr;
        *(u16x4*)(QAO + (long)(b * Sz + s0 + q) * 2048 + h * HDz + d) = pk;
    }
}

extern "C" void kernel_launch(void* const* d_in, const int* in_sizes, int n_in,
                              void* d_out, int out_size, void* d_ws, size_t ws_size,
                              hipStream_t stream) {
    const float* x = (const float*)d_in[0];
    const int* anchor = (const int*)d_in[1];
    const float* Wq = (const float*)d_in[2];
    const float* Wk = (const float*)d_in[3];
    const float* Wv = (const float*)d_in[4];
    const float* Wo = (const float*)d_in[5];

    char* ws = (char*)d_ws;
    const size_t XB = 67108864;   // x bf16: 16384*2048*2
    const size_t WB = 8388608;    // one weight bf16: 2048*2048*2
    u16* xbf = (u16*)(ws);
    u16* WqT = (u16*)(ws + XB);
    u16* WkT = (u16*)(ws + XB + WB);
    u16* WvT = (u16*)(ws + XB + 2 * WB);
    u16* WoT = (u16*)(ws + XB + 3 * WB);
    u16* Qb  = (u16*)(ws + XB + 4 * WB);            // Q, then attn out (aliased, disjoint tiles)
    float* kvpart = (float*)(ws + XB + 4 * WB);     // overlays Qb: used BEFORE Q-gemm writes it
    u16* ksp = (u16*)(ws + 2 * XB + 4 * WB);        // (B*H,128,128)
    u16* vspT= (u16*)(ws + 2 * XB + 4 * WB + 2097152);

    cvt_x<<<16384, 256, 0, stream>>>(x, xbf);
    transpose_cvt<<<dim3(64, 64, 4), dim3(32, 8), 0, stream>>>(Wq, Wk, Wv, Wo, WqT, WkT, WvT, WoT);
    kv_sparse<<<dim3(64, 2, KV_SPLIT), 256, 0, stream>>>(xbf, WkT, WvT, anchor, kvpart);
    kv_reduce<<<2048, 256, 0, stream>>>(kvpart, ksp);
    gemm256<u16><<<dim3(512), dim3(512), 0, stream>>>(xbf, WqT, Qb, 16384, 2048, 2048);
    attn_kernel<<<dim3(32, 16, 4), dim3(512), 0, stream>>>(Qb, ksp, vspT, anchor);
    gemm256<float><<<dim3(512), dim3(512), 0, stream>>>(Qb, WoT, (float*)d_out, 16384, 2048, 2048);
}